// Round 6
// baseline (4353.981 us; speedup 1.0000x reference)
//
#include <hip/hip_runtime.h>

// ---------------------------------------------------------------------------
// MEASUREMENT ROUND: round-5 pipeline with internal repeat loops so the three
// main kernels exceed the ~440us harness fills and surface in rocprof top-5.
// Reps are idempotent (same values rewritten) -> correctness unchanged.
//   gemm x4, lif x40, readout x80. Divide counters by rep count.
// ---------------------------------------------------------------------------

typedef float  f32x4  __attribute__((ext_vector_type(4)));
typedef short  short8 __attribute__((ext_vector_type(8)));
typedef unsigned long long ull;

#define B_   256
#define T_   1000
#define K_   700
#define H_   64
#define O_   20
#define NKT  22          // ceil(700/32) k-tiles of BK=32
#define TC   10          // v_ro scan chunk length
#define NC   100         // number of v_ro chunks
#define TCL  100         // LIF chunk length
#define NCL  10          // LIF chunks
#define BIL  40          // LIF burn-in steps

#define REP_G 4
#define REP_L 40
#define REP_R 80

// workspace layout (bytes)
#define OFF_WFRAG  ((size_t)0)            // 22*8192 = 180,224
#define OFF_CUR    ((size_t)262144)       // 256000*64*4 = 65,536,000
#define OFF_MASK   ((size_t)65798144)     // 256000*8    =  2,048,000

// ---------------------------------------------------------------------------
// k0: pack W_h into fragment-ordered split-bf16, BK=32 tiles (zero-pad k>=700).
// ---------------------------------------------------------------------------
__global__ void wprep(const float* __restrict__ Wh, unsigned short* __restrict__ wfrag) {
    int e = blockIdx.x * 256 + threadIdx.x;          // 22*256 = 5632 exact
    int kt   = e >> 8;
    int rem  = e & 255;
    int nf   = rem >> 6;
    int lane = rem & 63;
    int h     = nf * 16 + (lane & 15);
    int kbase = kt * 32 + ((lane >> 4) & 3) * 8;
    unsigned short* dh = wfrag + (size_t)kt * 4096 + (nf * 64 + lane) * 8;
    unsigned short* dl = dh + 2048;
#pragma unroll
    for (int j = 0; j < 8; ++j) {
        int k = kbase + j;
        float v = (k < K_) ? Wh[(size_t)h * K_ + k] : 0.0f;
        unsigned u  = __builtin_bit_cast(unsigned, v);
        float    fh = __builtin_bit_cast(float, u & 0xffff0000u);
        float    r  = v - fh;
        dh[j] = (unsigned short)(u >> 16);
        dl[j] = (unsigned short)(__builtin_bit_cast(unsigned, r) >> 16);
    }
}

// ---------------------------------------------------------------------------
// k1: GEMM (round-5 structure, x REP_G internal repeats)
// ---------------------------------------------------------------------------
__device__ __forceinline__ void glds16(const void* src, void* lds) {
    __builtin_amdgcn_global_load_lds(
        (const __attribute__((address_space(1))) void*)src,
        (__attribute__((address_space(3))) void*)lds, 16, 0, 0);
}

__device__ __forceinline__ void splitpair(f32x4 p0, f32x4 p1, short8& hi, short8& lo) {
#pragma unroll
    for (int j = 0; j < 4; ++j) {
        {
            unsigned u  = __builtin_bit_cast(unsigned, p0[j]);
            float    fh = __builtin_bit_cast(float, u & 0xffff0000u);
            float    r  = p0[j] - fh;
            hi[j] = (short)(u >> 16);
            lo[j] = (short)(__builtin_bit_cast(unsigned, r) >> 16);
        }
        {
            unsigned u  = __builtin_bit_cast(unsigned, p1[j]);
            float    fh = __builtin_bit_cast(float, u & 0xffff0000u);
            float    r  = p1[j] - fh;
            hi[j + 4] = (short)(u >> 16);
            lo[j + 4] = (short)(__builtin_bit_cast(unsigned, r) >> 16);
        }
    }
}

__device__ __forceinline__ void stage_x32(const float* __restrict__ x, size_t row0,
                                          int kt, int lane, int wid, float* sbuf) {
#pragma unroll
    for (int j = 0; j < 4; ++j) {
        int c   = j * 256 + wid * 64 + lane;
        int row = c >> 3;
        int col = c & 7;
        int csw = (col ^ (row & 7)) << 4;        // pre-swizzled source byte col
        int kbyte = kt * 128 + csw;
        if (kbyte + 16 > K_ * 4) kbyte = 0;      // tail clamp; value * W_pad(0) = 0
        const char* src = (const char*)(x + (row0 + row) * (size_t)K_) + kbyte;
        float* dst = sbuf + (size_t)(j * 256 + wid * 64) * 4;  // wave-uniform base
        glds16(src, dst);
    }
}

__device__ __forceinline__ void stage_w32(const unsigned short* __restrict__ wfrag,
                                          int kt, int lane, int wid, unsigned short* sbuf) {
#pragma unroll
    for (int j = 0; j < 2; ++j) {
        int c = j * 256 + wid * 64 + lane;
        int l = c ^ ((c >> 4) & 7);
        const unsigned short* src = wfrag + (size_t)kt * 4096 + l * 8;
        unsigned short* dst = sbuf + (size_t)(j * 256 + wid * 64) * 8;   // wave-uniform base
        glds16(src, dst);
    }
}

__device__ __forceinline__ void compute32(const float* sbx_, const unsigned short* sbw_,
                                          int lane, int wid, f32x4 (&acc)[2][4]) {
    const f32x4*  xb = (const f32x4*)sbx_;
    const short8* wb = (const short8*)sbw_;
    short8 ah[2], al[2];
    int v0 = (lane >> 4) * 2;
#pragma unroll
    for (int i = 0; i < 2; ++i) {
        int r  = wid * 32 + i * 16 + (lane & 15);
        int c0 = r * 8 + (v0 ^ (r & 7));
        int c1 = r * 8 + ((v0 + 1) ^ (r & 7));
        splitpair(xb[c0], xb[c1], ah[i], al[i]);
    }
#pragma unroll
    for (int n = 0; n < 4; ++n) {
        int lh = n * 64 + lane;
        int ph = lh ^ ((lh >> 4) & 7);
        short8 bhf = wb[ph];
        short8 blf = wb[ph + 256];
#pragma unroll
        for (int i = 0; i < 2; ++i) {
            acc[i][n] = __builtin_amdgcn_mfma_f32_16x16x32_bf16(ah[i], bhf, acc[i][n], 0, 0, 0);
            acc[i][n] = __builtin_amdgcn_mfma_f32_16x16x32_bf16(al[i], bhf, acc[i][n], 0, 0, 0);
            acc[i][n] = __builtin_amdgcn_mfma_f32_16x16x32_bf16(ah[i], blf, acc[i][n], 0, 0, 0);
        }
    }
}

__global__ __launch_bounds__(256, 2) void gemm_cur(const float* __restrict__ x,
                                                   const unsigned short* __restrict__ wfrag,
                                                   const float* __restrict__ b_h,
                                                   float* __restrict__ cur) {
    __shared__ float          sbx[3][4096];   // 3 x 16KB x-tiles
    __shared__ unsigned short sbw[3][4096];   // 3 x  8KB W-tiles
    int tid  = threadIdx.x;
    int lane = tid & 63;
    int wid  = tid >> 6;             // 0..3
    size_t row0 = (size_t)blockIdx.x * 128;

    float bh4[4];
#pragma unroll
    for (int n = 0; n < 4; ++n) bh4[n] = b_h[n * 16 + (lane & 15)];

    for (int rep = 0; rep < REP_G; ++rep) {
        __syncthreads();   // LDS reuse fence across reps

        f32x4 acc[2][4];
#pragma unroll
        for (int i = 0; i < 2; ++i)
#pragma unroll
            for (int n = 0; n < 4; ++n) acc[i][n] = (f32x4){0.f, 0.f, 0.f, 0.f};

        stage_x32(x, row0, 0, lane, wid, sbx[0]);  stage_w32(wfrag, 0, lane, wid, sbw[0]);
        stage_x32(x, row0, 1, lane, wid, sbx[1]);  stage_w32(wfrag, 1, lane, wid, sbw[1]);
        stage_x32(x, row0, 2, lane, wid, sbx[2]);  stage_w32(wfrag, 2, lane, wid, sbw[2]);

#define GSTEP(T, N)                                                          \
    {                                                                        \
        asm volatile("s_waitcnt vmcnt(" #N ")" ::: "memory");                \
        __builtin_amdgcn_s_barrier();                                        \
        compute32(sbx[(T) % 3], sbw[(T) % 3], lane, wid, acc);               \
        asm volatile("s_waitcnt lgkmcnt(0)" ::: "memory");                   \
        __builtin_amdgcn_s_barrier();                                        \
        if ((T) + 3 < NKT) {                                                 \
            stage_x32(x, row0, (T) + 3, lane, wid, sbx[(T) % 3]);            \
            stage_w32(wfrag, (T) + 3, lane, wid, sbw[(T) % 3]);              \
        }                                                                    \
    }
        GSTEP(0, 12)  GSTEP(1, 12)  GSTEP(2, 12)  GSTEP(3, 12)  GSTEP(4, 12)
        GSTEP(5, 12)  GSTEP(6, 12)  GSTEP(7, 12)  GSTEP(8, 12)  GSTEP(9, 12)
        GSTEP(10, 12) GSTEP(11, 12) GSTEP(12, 12) GSTEP(13, 12) GSTEP(14, 12)
        GSTEP(15, 12) GSTEP(16, 12) GSTEP(17, 12) GSTEP(18, 12) GSTEP(19, 12)
        GSTEP(20, 6)  GSTEP(21, 0)
#undef GSTEP

#pragma unroll
        for (int i = 0; i < 2; ++i) {
            size_t row = row0 + wid * 32 + i * 16 + ((lane >> 4) & 3) * 4;
#pragma unroll
            for (int n = 0; n < 4; ++n) {
#pragma unroll
                for (int j = 0; j < 4; ++j) {
                    cur[(row + j) * H_ + n * 16 + (lane & 15)] = acc[i][n][j] + bh4[n];
                }
            }
        }
    }
}

// ---------------------------------------------------------------------------
// k2: LIF (round-5 structure, x REP_L internal repeats)
// ---------------------------------------------------------------------------
__global__ __launch_bounds__(64) void lif(const float* __restrict__ cur, ull* __restrict__ masks) {
    int b = blockIdx.x & 255;
    int c = blockIdx.x >> 8;
    int h = threadIdx.x;
    int t0 = c * TCL;
    int ts = (c == 0) ? 0 : (t0 - BIL);
    ull* mp = masks + (size_t)b * T_;
    for (int rep = 0; rep < REP_L; ++rep) {
        const float* p = cur + ((size_t)b * T_ + ts) * H_ + h;
        float v = 0.0f;
#pragma unroll 8
        for (int t = ts; t < t0; ++t) {
            float cc = *p; p += H_;
            v = (v + cc) * 0.5f;
            v = (v >= 1.0f) ? 0.0f : v;
        }
#pragma unroll 8
        for (int t = t0; t < t0 + TCL; ++t) {
            float cc = *p; p += H_;
            v = (v + cc) * 0.5f;
            bool s = (v >= 1.0f);
            ull m = __ballot(s);
            if (h == 0) mp[t] = m;
            v = s ? 0.0f : v;
        }
    }
}

// ---------------------------------------------------------------------------
// k3: fused readout (round-5 structure; phases x REP_R, init once)
// ---------------------------------------------------------------------------
__global__ __launch_bounds__(128) void readout(const ull* __restrict__ masks,
                                               const float* __restrict__ Wr,
                                               const float* __restrict__ br,
                                               const float* __restrict__ tau,
                                               float* __restrict__ out) {
    __shared__ __align__(16) float wt[64][20];     // wt[h][o]
    __shared__ ull  smask[T_];
    __shared__ __align__(16) float E[NC][20];
    __shared__ __align__(16) float Sv[NC][20];
    __shared__ __align__(16) float pacc[NC][20];
    __shared__ __align__(16) float sScale[20], sBase[20], sBeta[20];

    int tid = threadIdx.x;
    int b   = blockIdx.x;
    for (int i = tid; i < 1280; i += 128) wt[i & 63][i >> 6] = Wr[(size_t)(i >> 6) * 64 + (i & 63)];
    for (int i = tid; i < T_; i += 128) smask[i] = masks[(size_t)b * T_ + i];
    if (tid < 20) {
        float beta = 1.0f / (1.0f + __expf(-tau[tid]));
        sBeta[tid]  = beta;
        sScale[tid] = 1.0f - beta;
        sBase[tid]  = br[tid];
    }
    __syncthreads();

    for (int rep = 0; rep < REP_R; ++rep) {
        __syncthreads();

        // phase 1: scanE
        for (int it = tid; it < NC * 5; it += 128) {
            int o4 = it % 5;
            int c  = it / 5;
            f32x4 beta4  = *(const f32x4*)&sBeta[o4 * 4];
            f32x4 scale4 = *(const f32x4*)&sScale[o4 * 4];
            f32x4 base4  = *(const f32x4*)&sBase[o4 * 4];
            f32x4 v = {0.f, 0.f, 0.f, 0.f};
            const ull* mp = smask + c * TC;
            for (int j = 0; j < TC; ++j) {
                ull m = mp[j];
                f32x4 a = {0.f, 0.f, 0.f, 0.f};
                while (m) {
                    int h = __builtin_ctzll(m);
                    m &= (m - 1);
                    a += *(const f32x4*)&wt[h][o4 * 4];
                }
                f32x4 q;
#pragma unroll
                for (int jj = 0; jj < 4; ++jj) q[jj] = scale4[jj] * (base4[jj] + a[jj]);
                v = beta4 * v + q;
            }
            *(f32x4*)&E[c][o4 * 4] = v;
        }
        __syncthreads();

        // phase 2: carry
        if (tid < 20) {
            int o = tid;
            float beta = sBeta[o];
            float bp = 1.0f;
#pragma unroll
            for (int i = 0; i < TC; ++i) bp *= beta;
            float s = 0.0f;
            for (int c = 0; c < NC; ++c) {
                Sv[c][o] = s;
                s = bp * s + E[c][o];
            }
        }
        __syncthreads();

        // phase 3: scanSoft
        if (tid < NC) {
            int c = tid;
            float beta[20], v[20], acc[20];
#pragma unroll
            for (int o = 0; o < 20; ++o) {
                beta[o] = sBeta[o];
                v[o]   = Sv[c][o];
                acc[o] = 0.0f;
            }
            int t0 = c * TC;
            const ull* mp = smask + t0;
            for (int j = 0; j < TC; ++j) {
                int t = t0 + j;
                ull m = mp[j];
                f32x4 a[5];
#pragma unroll
                for (int i = 0; i < 5; ++i) a[i] = (f32x4){0.f, 0.f, 0.f, 0.f};
                while (m) {
                    int h = __builtin_ctzll(m);
                    m &= (m - 1);
                    const f32x4* w4 = (const f32x4*)&wt[h][0];
#pragma unroll
                    for (int i = 0; i < 5; ++i) a[i] += w4[i];
                }
#pragma unroll
                for (int o = 0; o < 20; ++o) {
                    float q = sScale[o] * (sBase[o] + a[o >> 2][o & 3]);
                    v[o] = beta[o] * v[o] + q;
                }
                if (t >= 11) {
                    float mx = v[0];
#pragma unroll
                    for (int o = 1; o < 20; ++o) mx = fmaxf(mx, v[o]);
                    float e[20], ssum = 0.0f;
#pragma unroll
                    for (int o = 0; o < 20; ++o) { e[o] = __expf(v[o] - mx); ssum += e[o]; }
                    float inv = 1.0f / ssum;
#pragma unroll
                    for (int o = 0; o < 20; ++o) acc[o] += e[o] * inv;
                }
            }
#pragma unroll
            for (int o = 0; o < 20; ++o) pacc[c][o] = acc[o];
        }
        __syncthreads();

        // phase 4: reduce
        if (tid < 20) {
            float s = 0.0f;
            for (int c = 0; c < NC; ++c) s += pacc[c][tid];
            out[(size_t)b * 20 + tid] = s;
        }
    }
}

// ---------------------------------------------------------------------------
extern "C" void kernel_launch(void* const* d_in, const int* in_sizes, int n_in,
                              void* d_out, int out_size, void* d_ws, size_t ws_size,
                              hipStream_t stream) {
    const float* x   = (const float*)d_in[0];
    const float* W_h = (const float*)d_in[1];
    const float* b_h = (const float*)d_in[2];
    const float* W_r = (const float*)d_in[3];
    const float* b_r = (const float*)d_in[4];
    const float* tau = (const float*)d_in[5];

    char* ws = (char*)d_ws;
    unsigned short* wfrag = (unsigned short*)(ws + OFF_WFRAG);
    float* cur  = (float*)(ws + OFF_CUR);
    ull*   msk  = (ull*)(ws + OFF_MASK);
    float* out  = (float*)d_out;

    wprep<<<22, 256, 0, stream>>>(W_h, wfrag);
    gemm_cur<<<2000, 256, 0, stream>>>(x, wfrag, b_h, cur);
    lif<<<NCL * 256, 64, 0, stream>>>(cur, msk);
    readout<<<256, 128, 0, stream>>>(msk, W_r, b_r, tau, out);
}

// Round 7
// 218.254 us; speedup vs baseline: 19.9491x; 19.9491x over previous
//
#include <hip/hip_runtime.h>

// ---------------------------------------------------------------------------
// VanillaSFNN: x[256,1000,700] -> currents GEMM -> LIF spikes -> readout leaky
// integrator + softmax accumulation.
//
// Pipeline (4 launches):
//   k0 wprep  : W_h f32 -> split bf16 hi/lo packed in MFMA fragment order (BK=32)
//   k1 gemm   : 3-term split-bf16 MFMA; x+W staged via global_load_lds,
//               ring-2 double buffer, 3 blocks/CU (TLP covers latency).
//               cur written in t-quad layout [r/4][h][4] (dwordx4 stores).
//   k2 lif    : chunked speculative scan; lane=h loads f32x4 = 4 t-steps
//               (coalesced 1KB/wave-op); spikes -> ballot masks
//   k3 readout: per-batch fused scan, 512 thr, TC=5/NC=200, parallel carry
// ---------------------------------------------------------------------------

typedef float  f32x4  __attribute__((ext_vector_type(4)));
typedef short  short8 __attribute__((ext_vector_type(8)));
typedef unsigned long long ull;

#define B_   256
#define T_   1000
#define K_   700
#define H_   64
#define O_   20
#define NKT  22          // ceil(700/32) k-tiles of BK=32
#define NCH  200         // v_ro chunks
#define TCH  5           // chunk length (NCH*TCH = T_)
#define TCL  100         // LIF chunk length
#define NCL  10          // LIF chunks
#define BIL  40          // LIF burn-in steps

// workspace layout (bytes)
#define OFF_WFRAG  ((size_t)0)            // 22*8192 = 180,224
#define OFF_CUR    ((size_t)262144)       // 256000*64*4 = 65,536,000
#define OFF_MASK   ((size_t)65798144)     // 256000*8    =  2,048,000

// ---------------------------------------------------------------------------
// k0: pack W_h into fragment-ordered split-bf16, BK=32 tiles (zero-pad k>=700).
// Slot s = n*64+lane holds 8 bf16: h = n*16+(lane&15), k = kt*32+((lane>>4)&3)*8+j
// ---------------------------------------------------------------------------
__global__ void wprep(const float* __restrict__ Wh, unsigned short* __restrict__ wfrag) {
    int e = blockIdx.x * 256 + threadIdx.x;          // 22*256 = 5632 exact
    int kt   = e >> 8;
    int rem  = e & 255;
    int nf   = rem >> 6;
    int lane = rem & 63;
    int h     = nf * 16 + (lane & 15);
    int kbase = kt * 32 + ((lane >> 4) & 3) * 8;
    unsigned short* dh = wfrag + (size_t)kt * 4096 + (nf * 64 + lane) * 8;
    unsigned short* dl = dh + 2048;
#pragma unroll
    for (int j = 0; j < 8; ++j) {
        int k = kbase + j;
        float v = (k < K_) ? Wh[(size_t)h * K_ + k] : 0.0f;
        unsigned u  = __builtin_bit_cast(unsigned, v);
        float    fh = __builtin_bit_cast(float, u & 0xffff0000u);
        float    r  = v - fh;
        dh[j] = (unsigned short)(u >> 16);
        dl[j] = (unsigned short)(__builtin_bit_cast(unsigned, r) >> 16);
    }
}

// ---------------------------------------------------------------------------
// k1: GEMM  currents[r][h] = sum_k x[r][k]*W_h[h][k] + b_h[h]
// ---------------------------------------------------------------------------
__device__ __forceinline__ void glds16(const void* src, void* lds) {
    __builtin_amdgcn_global_load_lds(
        (const __attribute__((address_space(1))) void*)src,
        (__attribute__((address_space(3))) void*)lds, 16, 0, 0);
}

__device__ __forceinline__ void splitpair(f32x4 p0, f32x4 p1, short8& hi, short8& lo) {
#pragma unroll
    for (int j = 0; j < 4; ++j) {
        {
            unsigned u  = __builtin_bit_cast(unsigned, p0[j]);
            float    fh = __builtin_bit_cast(float, u & 0xffff0000u);
            float    r  = p0[j] - fh;
            hi[j] = (short)(u >> 16);
            lo[j] = (short)(__builtin_bit_cast(unsigned, r) >> 16);
        }
        {
            unsigned u  = __builtin_bit_cast(unsigned, p1[j]);
            float    fh = __builtin_bit_cast(float, u & 0xffff0000u);
            float    r  = p1[j] - fh;
            hi[j + 4] = (short)(u >> 16);
            lo[j + 4] = (short)(__builtin_bit_cast(unsigned, r) >> 16);
        }
    }
}

// stage one x-tile: 128 rows x 32 k = 16KB; LDS phys (row,pcol) holds logical
// col (pcol ^ (row&7)) -> source pre-swizzled.
__device__ __forceinline__ void stage_x32(const float* __restrict__ x, size_t row0,
                                          int kt, int lane, int wid, float* sbuf) {
#pragma unroll
    for (int j = 0; j < 4; ++j) {
        int c   = j * 256 + wid * 64 + lane;
        int row = c >> 3;
        int col = c & 7;
        int csw = (col ^ (row & 7)) << 4;        // pre-swizzled source byte col
        int kbyte = kt * 128 + csw;
        if (kbyte + 16 > K_ * 4) kbyte = 0;      // tail clamp; value * W_pad(0) = 0
        const char* src = (const char*)(x + (row0 + row) * (size_t)K_) + kbyte;
        float* dst = sbuf + (size_t)(j * 256 + wid * 64) * 4;  // wave-uniform base
        glds16(src, dst);
    }
}

// stage one W-tile: 8KB; LDS phys chunk c holds logical c ^ ((c>>4)&7).
__device__ __forceinline__ void stage_w32(const unsigned short* __restrict__ wfrag,
                                          int kt, int lane, int wid, unsigned short* sbuf) {
#pragma unroll
    for (int j = 0; j < 2; ++j) {
        int c = j * 256 + wid * 64 + lane;
        int l = c ^ ((c >> 4) & 7);
        const unsigned short* src = wfrag + (size_t)kt * 4096 + l * 8;
        unsigned short* dst = sbuf + (size_t)(j * 256 + wid * 64) * 8;   // wave-uniform base
        glds16(src, dst);
    }
}

__device__ __forceinline__ void compute32(const float* sbx_, const unsigned short* sbw_,
                                          int lane, int wid, f32x4 (&acc)[2][4]) {
    const f32x4*  xb = (const f32x4*)sbx_;
    const short8* wb = (const short8*)sbw_;
    short8 ah[2], al[2];
    int v0 = (lane >> 4) * 2;
#pragma unroll
    for (int i = 0; i < 2; ++i) {
        int r  = wid * 32 + i * 16 + (lane & 15);
        int c0 = r * 8 + (v0 ^ (r & 7));
        int c1 = r * 8 + ((v0 + 1) ^ (r & 7));
        splitpair(xb[c0], xb[c1], ah[i], al[i]);
    }
#pragma unroll
    for (int n = 0; n < 4; ++n) {
        int lh = n * 64 + lane;
        int ph = lh ^ ((lh >> 4) & 7);
        short8 bhf = wb[ph];
        short8 blf = wb[ph + 256];
#pragma unroll
        for (int i = 0; i < 2; ++i) {
            acc[i][n] = __builtin_amdgcn_mfma_f32_16x16x32_bf16(ah[i], bhf, acc[i][n], 0, 0, 0);
            acc[i][n] = __builtin_amdgcn_mfma_f32_16x16x32_bf16(al[i], bhf, acc[i][n], 0, 0, 0);
            acc[i][n] = __builtin_amdgcn_mfma_f32_16x16x32_bf16(ah[i], blf, acc[i][n], 0, 0, 0);
        }
    }
}

__global__ __launch_bounds__(256, 3) void gemm_cur(const float* __restrict__ x,
                                                   const unsigned short* __restrict__ wfrag,
                                                   const float* __restrict__ b_h,
                                                   float* __restrict__ cur) {
    __shared__ float          sbx[2][4096];   // 2 x 16KB x-tiles
    __shared__ unsigned short sbw[2][4096];   // 2 x  8KB W-tiles
    int tid  = threadIdx.x;
    int lane = tid & 63;
    int wid  = tid >> 6;             // 0..3
    size_t row0 = (size_t)blockIdx.x * 128;

    float bh4[4];
#pragma unroll
    for (int n = 0; n < 4; ++n) bh4[n] = b_h[n * 16 + (lane & 15)];

    f32x4 acc[2][4];
#pragma unroll
    for (int i = 0; i < 2; ++i)
#pragma unroll
        for (int n = 0; n < 4; ++n) acc[i][n] = (f32x4){0.f, 0.f, 0.f, 0.f};

    // prologue: stage tiles 0,1 (6 glds each -> 12 outstanding)
    stage_x32(x, row0, 0, lane, wid, sbx[0]);  stage_w32(wfrag, 0, lane, wid, sbw[0]);
    stage_x32(x, row0, 1, lane, wid, sbx[1]);  stage_w32(wfrag, 1, lane, wid, sbw[1]);

#define GSTEP(T, N)                                                          \
    {                                                                        \
        asm volatile("s_waitcnt vmcnt(" #N ")" ::: "memory");                \
        __builtin_amdgcn_s_barrier();                                        \
        compute32(sbx[(T) & 1], sbw[(T) & 1], lane, wid, acc);               \
        asm volatile("s_waitcnt lgkmcnt(0)" ::: "memory");                   \
        __builtin_amdgcn_s_barrier();                                        \
        if ((T) + 2 < NKT) {                                                 \
            stage_x32(x, row0, (T) + 2, lane, wid, sbx[(T) & 1]);            \
            stage_w32(wfrag, (T) + 2, lane, wid, sbw[(T) & 1]);              \
        }                                                                    \
    }
    GSTEP(0, 6)   GSTEP(1, 6)   GSTEP(2, 6)   GSTEP(3, 6)   GSTEP(4, 6)
    GSTEP(5, 6)   GSTEP(6, 6)   GSTEP(7, 6)   GSTEP(8, 6)   GSTEP(9, 6)
    GSTEP(10, 6)  GSTEP(11, 6)  GSTEP(12, 6)  GSTEP(13, 6)  GSTEP(14, 6)
    GSTEP(15, 6)  GSTEP(16, 6)  GSTEP(17, 6)  GSTEP(18, 6)  GSTEP(19, 6)
    GSTEP(20, 6)  GSTEP(21, 0)
#undef GSTEP

    // epilogue: t-quad layout cur4[(r>>2)*64 + h] = {rows r..r+3} (16B stores)
    f32x4* cur4 = (f32x4*)cur;
#pragma unroll
    for (int i = 0; i < 2; ++i) {
        size_t r4 = row0 + wid * 32 + i * 16 + ((lane >> 4) & 3) * 4;
#pragma unroll
        for (int n = 0; n < 4; ++n) {
            f32x4 q;
#pragma unroll
            for (int j = 0; j < 4; ++j) q[j] = acc[i][n][j] + bh4[n];
            cur4[(r4 >> 2) * 64 + n * 16 + (lane & 15)] = q;
        }
    }
}

// ---------------------------------------------------------------------------
// k2: LIF, chunked speculative. One wave per (batch, chunk); lane = neuron.
// t-quad cur layout: lane h loads f32x4 = 4 consecutive t's (coalesced 1KB/op).
// ---------------------------------------------------------------------------
__global__ __launch_bounds__(64) void lif(const float* __restrict__ cur, ull* __restrict__ masks) {
    int b = blockIdx.x & 255;
    int c = blockIdx.x >> 8;
    int h = threadIdx.x;
    int t0 = c * TCL;
    int ts = (c == 0) ? 0 : (t0 - BIL);
    const f32x4* p = (const f32x4*)cur + (((size_t)b * T_ + ts) >> 2) * 64 + h;
    float v = 0.0f;
    int ngb = (t0 - ts) >> 2;          // burn-in groups (0 or 10)
    for (int g = 0; g < ngb; ++g) {
        f32x4 q = p[g * 64];
#pragma unroll
        for (int j = 0; j < 4; ++j) {
            v = (v + q[j]) * 0.5f;
            v = (v >= 1.0f) ? 0.0f : v;
        }
    }
    p += (size_t)ngb * 64;
    ull* mp = masks + (size_t)b * T_ + t0;
#pragma unroll 2
    for (int g = 0; g < TCL / 4; ++g) {
        f32x4 q = p[g * 64];
#pragma unroll
        for (int j = 0; j < 4; ++j) {
            v = (v + q[j]) * 0.5f;
            bool s = (v >= 1.0f);
            ull m = __ballot(s);
            if (h == 0) mp[g * 4 + j] = m;
            v = s ? 0.0f : v;
        }
    }
}

// ---------------------------------------------------------------------------
// k3: fused readout, one block per batch, 512 threads (8 waves).
// TC=5, NC=200; carry and reduce parallelized over (o, group-of-25).
// ---------------------------------------------------------------------------
__global__ __launch_bounds__(512) void readout(const ull* __restrict__ masks,
                                               const float* __restrict__ Wr,
                                               const float* __restrict__ br,
                                               const float* __restrict__ tau,
                                               float* __restrict__ out) {
    __shared__ __align__(16) float wt[64][20];     // wt[h][o]
    __shared__ ull  smask[T_];
    __shared__ __align__(16) float E[NCH][20];
    __shared__ __align__(16) float Sv[NCH][20];
    __shared__ __align__(16) float pacc[NCH][20];
    __shared__ __align__(16) float sScale[20], sBase[20], sBeta[20];
    __shared__ float Pg[8][20], Sst[8][20], part[8][20];

    int tid = threadIdx.x;
    int b   = blockIdx.x;
    for (int i = tid; i < 1280; i += 512) wt[i & 63][i >> 6] = Wr[(size_t)(i >> 6) * 64 + (i & 63)];
    for (int i = tid; i < T_; i += 512) smask[i] = masks[(size_t)b * T_ + i];
    if (tid < 20) {
        float beta = 1.0f / (1.0f + __expf(-tau[tid]));
        sBeta[tid]  = beta;
        sScale[tid] = 1.0f - beta;
        sBase[tid]  = br[tid];
    }
    __syncthreads();

    // phase 1: scanE — items (c, o4), NCH*5 = 1000
    for (int it = tid; it < NCH * 5; it += 512) {
        int o4 = it % 5;
        int c  = it / 5;
        f32x4 beta4  = *(const f32x4*)&sBeta[o4 * 4];
        f32x4 scale4 = *(const f32x4*)&sScale[o4 * 4];
        f32x4 base4  = *(const f32x4*)&sBase[o4 * 4];
        f32x4 v = {0.f, 0.f, 0.f, 0.f};
        const ull* mp = smask + c * TCH;
#pragma unroll
        for (int j = 0; j < TCH; ++j) {
            ull m = mp[j];
            f32x4 a = {0.f, 0.f, 0.f, 0.f};
            while (m) {
                int h = __builtin_ctzll(m);
                m &= (m - 1);
                a += *(const f32x4*)&wt[h][o4 * 4];
            }
            f32x4 q;
#pragma unroll
            for (int jj = 0; jj < 4; ++jj) q[jj] = scale4[jj] * (base4[jj] + a[jj]);
            v = beta4 * v + q;
        }
        *(f32x4*)&E[c][o4 * 4] = v;
    }
    __syncthreads();

    // phase 2a: per-(o, g) partial combine over 25 chunks
    if (tid < 160) {
        int o = tid >> 3, g = tid & 7;
        float beta = sBeta[o];
        float b2 = beta * beta;
        float bp = b2 * b2 * beta;               // beta^5
        float P = 0.0f;
        for (int c = g * 25; c < g * 25 + 25; ++c) P = bp * P + E[c][o];
        Pg[g][o] = P;
    }
    __syncthreads();

    // phase 2b: serial combine of 8 groups per o
    if (tid < 20) {
        int o = tid;
        float beta = sBeta[o];
        float b2 = beta * beta;
        float bp = b2 * b2 * beta;
        float bp25 = 1.0f;
#pragma unroll
        for (int i = 0; i < 25; ++i) bp25 *= bp;
        float s = 0.0f;
        for (int g = 0; g < 8; ++g) { Sst[g][o] = s; s = bp25 * s + Pg[g][o]; }
    }
    __syncthreads();

    // phase 2c: re-scan groups to produce per-chunk starts Sv
    if (tid < 160) {
        int o = tid >> 3, g = tid & 7;
        float beta = sBeta[o];
        float b2 = beta * beta;
        float bp = b2 * b2 * beta;
        float s = Sst[g][o];
        for (int c = g * 25; c < g * 25 + 25; ++c) { Sv[c][o] = s; s = bp * s + E[c][o]; }
    }
    __syncthreads();

    // phase 3: scanSoft — thread c < NCH
    if (tid < NCH) {
        int c = tid;
        float beta[20], v[20], acc[20];
#pragma unroll
        for (int o = 0; o < 20; ++o) {
            beta[o] = sBeta[o];
            v[o]   = Sv[c][o];
            acc[o] = 0.0f;
        }
        int t0 = c * TCH;
        const ull* mp = smask + t0;
#pragma unroll
        for (int j = 0; j < TCH; ++j) {
            int t = t0 + j;
            ull m = mp[j];
            f32x4 a[5];
#pragma unroll
            for (int i = 0; i < 5; ++i) a[i] = (f32x4){0.f, 0.f, 0.f, 0.f};
            while (m) {
                int h = __builtin_ctzll(m);
                m &= (m - 1);
                const f32x4* w4 = (const f32x4*)&wt[h][0];
#pragma unroll
                for (int i = 0; i < 5; ++i) a[i] += w4[i];
            }
#pragma unroll
            for (int o = 0; o < 20; ++o) {
                float q = sScale[o] * (sBase[o] + a[o >> 2][o & 3]);
                v[o] = beta[o] * v[o] + q;
            }
            if (t >= 11) {
                float mx = v[0];
#pragma unroll
                for (int o = 1; o < 20; ++o) mx = fmaxf(mx, v[o]);
                float e[20], ssum = 0.0f;
#pragma unroll
                for (int o = 0; o < 20; ++o) { e[o] = __expf(v[o] - mx); ssum += e[o]; }
                float inv = 1.0f / ssum;
#pragma unroll
                for (int o = 0; o < 20; ++o) acc[o] += e[o] * inv;
            }
        }
#pragma unroll
        for (int o = 0; o < 20; ++o) pacc[c][o] = acc[o];
    }
    __syncthreads();

    // phase 4: reduce — partials then serial-8
    if (tid < 160) {
        int o = tid >> 3, g = tid & 7;
        float s = 0.0f;
        for (int c = g * 25; c < g * 25 + 25; ++c) s += pacc[c][o];
        part[g][o] = s;
    }
    __syncthreads();
    if (tid < 20) {
        float s = 0.0f;
#pragma unroll
        for (int g = 0; g < 8; ++g) s += part[g][tid];
        out[(size_t)b * 20 + tid] = s;
    }
}

// ---------------------------------------------------------------------------
extern "C" void kernel_launch(void* const* d_in, const int* in_sizes, int n_in,
                              void* d_out, int out_size, void* d_ws, size_t ws_size,
                              hipStream_t stream) {
    const float* x   = (const float*)d_in[0];
    const float* W_h = (const float*)d_in[1];
    const float* b_h = (const float*)d_in[2];
    const float* W_r = (const float*)d_in[3];
    const float* b_r = (const float*)d_in[4];
    const float* tau = (const float*)d_in[5];

    char* ws = (char*)d_ws;
    unsigned short* wfrag = (unsigned short*)(ws + OFF_WFRAG);
    float* cur  = (float*)(ws + OFF_CUR);
    ull*   msk  = (ull*)(ws + OFF_MASK);
    float* out  = (float*)d_out;

    wprep<<<22, 256, 0, stream>>>(W_h, wfrag);
    gemm_cur<<<2000, 256, 0, stream>>>(x, wfrag, b_h, cur);
    lif<<<NCL * 256, 64, 0, stream>>>(cur, msk);
    readout<<<256, 512, 0, stream>>>(msk, W_r, b_r, tau, out);
}